// Round 3
// baseline (2545.686 us; speedup 1.0000x reference)
//
#include <hip/hip_runtime.h>
#include <hip/hip_bf16.h>
#include <cstdint>
#include <cstddef>

#define T_TOK 4096
#define DMODEL 2048
#define DFF 8192
#define NEXP 8
#define NPAIR (T_TOK * 2)

typedef __bf16 bf16_t;
typedef __bf16 bf16x8 __attribute__((ext_vector_type(8)));
typedef float fx4 __attribute__((ext_vector_type(4)));

__device__ __forceinline__ void gload16(const bf16_t* src, bf16_t* dst) {
    __builtin_amdgcn_global_load_lds(
        (const __attribute__((address_space(1))) uint32_t*)(src),
        (__attribute__((address_space(3))) uint32_t*)(dst), 16, 0, 0);
}

__device__ __forceinline__ bf16x8 pack8(const fx4 lo, const fx4 hi) {
    bf16x8 o;
    o[0] = (bf16_t)lo[0]; o[1] = (bf16_t)lo[1]; o[2] = (bf16_t)lo[2]; o[3] = (bf16_t)lo[3];
    o[4] = (bf16_t)hi[0]; o[5] = (bf16_t)hi[1]; o[6] = (bf16_t)hi[2]; o[7] = (bf16_t)hi[3];
    return o;
}

// ---------------- router ----------------
__global__ void router_kernel(const float* __restrict__ gating, int* __restrict__ counts,
                              int* __restrict__ tok_list, float* __restrict__ w_list) {
    int t = blockIdx.x * blockDim.x + threadIdx.x;
    if (t >= T_TOK) return;
    float l[NEXP];
    float mx = -1e30f;
#pragma unroll
    for (int e = 0; e < NEXP; e++) { l[e] = gating[t * NEXP + e]; mx = fmaxf(mx, l[e]); }
#pragma unroll
    for (int e = 0; e < NEXP; e++) { l[e] = __expf(l[e] - mx); }
    int e0 = 0; float p0 = l[0];
#pragma unroll
    for (int e = 1; e < NEXP; e++) { if (l[e] > p0) { p0 = l[e]; e0 = e; } }
    int e1 = -1; float p1 = -1.0f;
#pragma unroll
    for (int e = 0; e < NEXP; e++) { if (e != e0 && l[e] > p1) { p1 = l[e]; e1 = e; } }
    float inv = 1.0f / (p0 + p1);
    int s0 = atomicAdd(&counts[e0], 1);
    tok_list[e0 * T_TOK + s0] = t; w_list[e0 * T_TOK + s0] = p0 * inv;
    int s1 = atomicAdd(&counts[e1], 1);
    tok_list[e1 * T_TOK + s1] = t; w_list[e1 * T_TOK + s1] = p1 * inv;
}

__global__ void scan_kernel(const int* __restrict__ counts, int* __restrict__ offsets) {
    if (threadIdx.x == 0 && blockIdx.x == 0) {
        int acc = 0;
        for (int e = 0; e < NEXP; e++) { offsets[e] = acc; acc += counts[e]; }
        offsets[NEXP] = acc;
    }
}

// ---------------- x fp32 -> bf16 ----------------
__global__ void cvt_x_kernel(const float* __restrict__ x, bf16_t* __restrict__ xb) {
    int i = blockIdx.x * blockDim.x + threadIdx.x;
    const fx4* src = (const fx4*)x;
    fx4 v0 = src[2 * i], v1 = src[2 * i + 1];
    *(bf16x8*)(xb + (size_t)i * 8) = pack8(v0, v1);
}

// ================= gate_up GEMM (pipelined, counted vmcnt) =================
// 512 thr = 8 waves (4M x 2Nh). tile: M=256 tokens, N=128 h-cols (=> 256 weight rows: 128 g + 128 u), BK=64.
// per wave: 64M x 64 h-cols, dual acc (g,u): accg[4][4], accu[4][4].
// A: bf16 via global_load_lds (pre-swizzled src). W: fp32 reg-staged -> cvt -> swizzled ds_write.
#define GU_NT (DMODEL / 64)   // 32

__global__ __launch_bounds__(512, 2) void gateup_kernel(
    const bf16_t* __restrict__ xb, const float* __restrict__ gup,
    const int* __restrict__ counts, const int* __restrict__ offsets,
    const int* __restrict__ tok_list, bf16_t* __restrict__ h_buf)
{
    // idx = (g2<<7)|(m<<3)|q : q=XCD, m=m-slot, g2=(e<<3)|(y>>3), panel y = q + 8*(g2&7)
    const int idx = blockIdx.x;
    const int q = idx & 7;
    const int rest = idx >> 3;
    const int mslot = rest & 15;
    const int g2 = rest >> 4;            // 0..63
    const int e = g2 >> 3;
    const int cnt = counts[e];
    const int mbase = mslot * 256;
    if (mbase >= cnt) return;
    const int y = q + 8 * (g2 & 7);      // 0..63
    const int nbase = y * 128;
    const int off_e = offsets[e];

    __shared__ __align__(16) bf16_t lds_a[2][256 * 64];
    __shared__ __align__(16) bf16_t lds_w[2][256 * 64];

    const int tid = threadIdx.x;
    const int lane = tid & 63;
    const int w = tid >> 6;
    const int wm = (w >> 1) * 64;
    const int wnh = (w & 1) * 64;

    // ---- A staging setup: 4 global_load_lds per wave, 8 rows per instr ----
    const bf16_t* a_src[4];
    int a_dstoff[4];
#pragma unroll
    for (int j = 0; j < 4; j++) {
        int row = (w * 4 + j) * 8 + (lane >> 3);
        int cs = (lane & 7) ^ (row & 7);
        int slot = mbase + row;
        int tok = tok_list[e * T_TOK + (slot < cnt ? slot : cnt - 1)];
        a_src[j] = xb + (size_t)tok * DMODEL + cs * 8;
        a_dstoff[j] = (w * 4 + j) * 512;
    }
    // ---- W staging setup: thread = half-row (32 floats), 8 dwordx4 / thread ----
    const int wrow = tid >> 1;           // 0..255 (0-127 gate, 128-255 up)
    const int whalf = tid & 1;
    const int grow = (wrow < 128) ? (nbase + wrow) : (DFF + nbase + (wrow - 128));
    const float* w_src = gup + (size_t)e * (2 * DFF) * DMODEL + (size_t)grow * DMODEL + whalf * 32;
    int w_doff[4];
#pragma unroll
    for (int c4 = 0; c4 < 4; c4++) {
        int c = whalf * 4 + c4;
        w_doff[c4] = wrow * 64 + ((c ^ (wrow & 7)) * 8);
    }

    fx4 accg[4][4] = {};
    fx4 accu[4][4] = {};
    fx4 wreg[8];

    // prologue: issue W(0) then A(0)
#pragma unroll
    for (int i = 0; i < 8; i++) wreg[i] = *(const fx4*)(w_src + i * 4);
#pragma unroll
    for (int j = 0; j < 4; j++) gload16(a_src[j], &lds_a[0][a_dstoff[j]]);

    for (int t = 0; t < GU_NT; ++t) {
        const int cur = t & 1;
        asm volatile("s_waitcnt vmcnt(4)" ::: "memory");   // W(t) regs ready
        bf16_t* wb = lds_w[cur];
#pragma unroll
        for (int c4 = 0; c4 < 4; c4++)
            *(bf16x8*)(&wb[w_doff[c4]]) = pack8(wreg[c4 * 2], wreg[c4 * 2 + 1]);
        if (t + 1 < GU_NT) {
            const float* ws = w_src + (t + 1) * 64;
#pragma unroll
            for (int i = 0; i < 8; i++) wreg[i] = *(const fx4*)(ws + i * 4);
#pragma unroll
            for (int j = 0; j < 4; j++)
                gload16(a_src[j] + (t + 1) * 64, &lds_a[cur ^ 1][a_dstoff[j]]);
            asm volatile("s_waitcnt vmcnt(12) lgkmcnt(0)" ::: "memory");  // A(t) landed, my ds_writes done
        } else {
            asm volatile("s_waitcnt vmcnt(0) lgkmcnt(0)" ::: "memory");
        }
        __builtin_amdgcn_s_barrier();
        asm volatile("" ::: "memory");

        const bf16_t* A = lds_a[cur];
        const bf16_t* W = lds_w[cur];
        __builtin_amdgcn_s_setprio(1);
#pragma unroll
        for (int kp = 0; kp < 2; kp++) {
            const int ke = kp * 4 + (lane >> 4);
            bf16x8 af[4], gf[4], uf[4];
#pragma unroll
            for (int m = 0; m < 4; m++) {
                int r = wm + m * 16 + (lane & 15);
                af[m] = *(const bf16x8*)(&A[r * 64 + ((ke ^ (r & 7)) * 8)]);
            }
#pragma unroll
            for (int n = 0; n < 4; n++) {
                int r = wnh + n * 16 + (lane & 15);
                gf[n] = *(const bf16x8*)(&W[r * 64 + ((ke ^ (r & 7)) * 8)]);
                uf[n] = *(const bf16x8*)(&W[(r + 128) * 64 + ((ke ^ (r & 7)) * 8)]);
            }
#pragma unroll
            for (int m = 0; m < 4; m++)
#pragma unroll
                for (int n = 0; n < 4; n++) {
                    accg[m][n] = __builtin_amdgcn_mfma_f32_16x16x32_bf16(af[m], gf[n], accg[m][n], 0, 0, 0);
                    accu[m][n] = __builtin_amdgcn_mfma_f32_16x16x32_bf16(af[m], uf[n], accu[m][n], 0, 0, 0);
                }
        }
        __builtin_amdgcn_s_setprio(0);
        asm volatile("" ::: "memory");
        __builtin_amdgcn_s_barrier();
    }

    // epilogue: h = silu(g) * u -> bf16
    const int colbase = nbase + wnh + (lane & 15);
#pragma unroll
    for (int m = 0; m < 4; m++) {
        int rb = wm + m * 16 + ((lane >> 4) * 4);
#pragma unroll
        for (int j = 0; j < 4; j++) {
            int slot = mbase + rb + j;
            if (slot < cnt) {
                size_t hrow = (size_t)(off_e + slot);
#pragma unroll
                for (int n = 0; n < 4; n++) {
                    float g = accg[m][n][j];
                    float u = accu[m][n][j];
                    float hv = g * u / (1.0f + __expf(-g));
                    h_buf[hrow * DFF + colbase + n * 16] = (bf16_t)hv;
                }
            }
        }
    }
}

// ================= down GEMM (pipelined) =================
// 512 thr = 8 waves (4M x 2N). tile: M=256 pairs, N=256 out-cols, BK=64, nt=128.
// per wave: 64M x 128N -> acc[4][8].
#define DN_NT (DFF / 64)      // 128

__global__ __launch_bounds__(512, 2) void down_kernel(
    const bf16_t* __restrict__ h_buf, const float* __restrict__ dwn,
    const int* __restrict__ counts, const int* __restrict__ offsets,
    const int* __restrict__ tok_list, const float* __restrict__ w_list,
    float* __restrict__ out)
{
    // idx = (e<<7)|(m<<3)|y : y=panel(=XCD), m=m-slot
    const int idx = blockIdx.x;
    const int y = idx & 7;
    const int rest = idx >> 3;
    const int mslot = rest & 15;
    const int e = rest >> 4;
    const int cnt = counts[e];
    const int mbase = mslot * 256;
    if (mbase >= cnt) return;
    const int nbase = y * 256;
    const int off_e = offsets[e];

    __shared__ __align__(16) bf16_t lds_a[2][256 * 64];
    __shared__ __align__(16) bf16_t lds_w[2][256 * 64];

    const int tid = threadIdx.x;
    const int lane = tid & 63;
    const int w = tid >> 6;
    const int wm = (w >> 1) * 64;
    const int wn = (w & 1) * 128;

    const bf16_t* a_src[4];
    int a_dstoff[4];
#pragma unroll
    for (int j = 0; j < 4; j++) {
        int row = (w * 4 + j) * 8 + (lane >> 3);
        int cs = (lane & 7) ^ (row & 7);
        int slot = mbase + row;
        int hrow = off_e + (slot < cnt ? slot : cnt - 1);
        a_src[j] = h_buf + (size_t)hrow * DFF + cs * 8;
        a_dstoff[j] = (w * 4 + j) * 512;
    }
    const int wrow = tid >> 1;
    const int whalf = tid & 1;
    const float* w_src = dwn + (size_t)e * DMODEL * DFF + (size_t)(nbase + wrow) * DFF + whalf * 32;
    int w_doff[4];
#pragma unroll
    for (int c4 = 0; c4 < 4; c4++) {
        int c = whalf * 4 + c4;
        w_doff[c4] = wrow * 64 + ((c ^ (wrow & 7)) * 8);
    }

    fx4 acc[4][8] = {};
    fx4 wreg[8];

#pragma unroll
    for (int i = 0; i < 8; i++) wreg[i] = *(const fx4*)(w_src + i * 4);
#pragma unroll
    for (int j = 0; j < 4; j++) gload16(a_src[j], &lds_a[0][a_dstoff[j]]);

    for (int t = 0; t < DN_NT; ++t) {
        const int cur = t & 1;
        asm volatile("s_waitcnt vmcnt(4)" ::: "memory");
        bf16_t* wb = lds_w[cur];
#pragma unroll
        for (int c4 = 0; c4 < 4; c4++)
            *(bf16x8*)(&wb[w_doff[c4]]) = pack8(wreg[c4 * 2], wreg[c4 * 2 + 1]);
        if (t + 1 < DN_NT) {
            const float* ws = w_src + (t + 1) * 64;
#pragma unroll
            for (int i = 0; i < 8; i++) wreg[i] = *(const fx4*)(ws + i * 4);
#pragma unroll
            for (int j = 0; j < 4; j++)
                gload16(a_src[j] + (t + 1) * 64, &lds_a[cur ^ 1][a_dstoff[j]]);
            asm volatile("s_waitcnt vmcnt(12) lgkmcnt(0)" ::: "memory");
        } else {
            asm volatile("s_waitcnt vmcnt(0) lgkmcnt(0)" ::: "memory");
        }
        __builtin_amdgcn_s_barrier();
        asm volatile("" ::: "memory");

        const bf16_t* A = lds_a[cur];
        const bf16_t* W = lds_w[cur];
        __builtin_amdgcn_s_setprio(1);
#pragma unroll
        for (int kp = 0; kp < 2; kp++) {
            const int ke = kp * 4 + (lane >> 4);
            bf16x8 af[4], bf[8];
#pragma unroll
            for (int m = 0; m < 4; m++) {
                int r = wm + m * 16 + (lane & 15);
                af[m] = *(const bf16x8*)(&A[r * 64 + ((ke ^ (r & 7)) * 8)]);
            }
#pragma unroll
            for (int n = 0; n < 8; n++) {
                int r = wn + n * 16 + (lane & 15);
                bf[n] = *(const bf16x8*)(&W[r * 64 + ((ke ^ (r & 7)) * 8)]);
            }
#pragma unroll
            for (int m = 0; m < 4; m++)
#pragma unroll
                for (int n = 0; n < 8; n++)
                    acc[m][n] = __builtin_amdgcn_mfma_f32_16x16x32_bf16(af[m], bf[n], acc[m][n], 0, 0, 0);
        }
        __builtin_amdgcn_s_setprio(0);
        asm volatile("" ::: "memory");
        __builtin_amdgcn_s_barrier();
    }

    const int colb = nbase + wn + (lane & 15);
#pragma unroll
    for (int m = 0; m < 4; m++) {
        int rb = wm + m * 16 + ((lane >> 4) * 4);
#pragma unroll
        for (int j = 0; j < 4; j++) {
            int slot = mbase + rb + j;
            if (slot < cnt) {
                int tok = tok_list[e * T_TOK + slot];
                float wgt = w_list[e * T_TOK + slot];
#pragma unroll
                for (int n = 0; n < 8; n++)
                    atomicAdd(&out[(size_t)tok * DMODEL + colb + n * 16], wgt * acc[m][n][j]);
            }
        }
    }
}

// ---------------- launch ----------------
extern "C" void kernel_launch(void* const* d_in, const int* in_sizes, int n_in,
                              void* d_out, int out_size, void* d_ws, size_t ws_size,
                              hipStream_t stream) {
    const float* x      = (const float*)d_in[0];
    const float* gating = (const float*)d_in[1];
    const float* gup    = (const float*)d_in[2];
    const float* dwn    = (const float*)d_in[3];
    float* out = (float*)d_out;

    char* ws = (char*)d_ws;
    int*    counts   = (int*)(ws + 0);
    int*    offsets  = (int*)(ws + 64);
    int*    tok_list = (int*)(ws + 128);
    float*  w_list   = (float*)(ws + 128 + 131072);
    bf16_t* xb       = (bf16_t*)(ws + 262400);
    bf16_t* h_buf    = (bf16_t*)(ws + 17039872);

    hipMemsetAsync(counts, 0, 64, stream);
    hipMemsetAsync(out, 0, (size_t)out_size * sizeof(float), stream);

    router_kernel<<<dim3(T_TOK / 256), dim3(256), 0, stream>>>(gating, counts, tok_list, w_list);
    scan_kernel<<<dim3(1), dim3(64), 0, stream>>>(counts, offsets);
    cvt_x_kernel<<<dim3(T_TOK * DMODEL / 8 / 256), dim3(256), 0, stream>>>(x, xb);

    // 8 XCD-slots * 16 m-slots * 64 (expert,panel-group) = 8192
    gateup_kernel<<<dim3(8192), dim3(512), 0, stream>>>(
        xb, gup, counts, offsets, tok_list, h_buf);

    // 8 panels(=XCD) * 16 m-slots * 8 experts = 1024
    down_kernel<<<dim3(1024), dim3(512), 0, stream>>>(
        h_buf, dwn, counts, offsets, tok_list, w_list, out);
}